// Round 1
// baseline (2431.206 us; speedup 1.0000x reference)
//
#include <hip/hip_runtime.h>

// SpatialEncodeAgent: segment_max of agent_encodings (N,C) into grid cells
// given flat coords in [0, B*S*S), output [B, C, S, S], 0 for empty cells.
//
// Strategy: monotone uint32 encoding of float32 so atomicMax(uint) == float max.
//   encode(f): u = bits(f); u >= 0 (non-neg float) -> u | 0x80000000
//                           u < 0  (neg float)     -> ~u
//   This is a strict order-preserving bijection for non-NaN floats, and no
//   real float encodes to key 0 -> key==0 marks "empty cell" after scatter.
// Scatter atomics go DIRECTLY into the final [B,C,S,S] layout in d_out
// (out_idx = (coord/10000)*C*10000 + c*10000 + coord%10000), then one
// elementwise in-place pass decodes keys and zeroes empties. No transpose, no
// workspace dependence.

#define S_DIM 100
#define CELLS_PER_B (S_DIM * S_DIM)  // 10000

__device__ __forceinline__ unsigned encode_f32(float f) {
    unsigned u = __float_as_uint(f);
    return (u & 0x80000000u) ? ~u : (u | 0x80000000u);
}

__device__ __forceinline__ float decode_key(unsigned k) {
    if (k == 0u) return 0.0f;  // empty cell
    return (k & 0x80000000u) ? __uint_as_float(k & 0x7FFFFFFFu)
                             : __uint_as_float(~k);
}

// One lane-task = (agent, 4 consecutive channels). 16 lanes cover one agent's
// 64 channels; a wave covers 4 agents -> 1KB coalesced float4 encoding reads.
__global__ void spatial_scatter_max(const float* __restrict__ enc,
                                    const int* __restrict__ coords,
                                    unsigned* __restrict__ grid,
                                    int n_agents, int C) {
    const long long total = (long long)n_agents * 16;  // C/4 == 16 tasks/agent
    const long long stride = (long long)gridDim.x * blockDim.x;
    for (long long i = (long long)blockIdx.x * blockDim.x + threadIdx.x;
         i < total; i += stride) {
        const int agent = (int)(i >> 4);
        const int c4 = ((int)i & 15) << 2;  // channel base: 0,4,...,60
        const int coord = coords[agent];
        const int b = coord / CELLS_PER_B;
        const int rem = coord - b * CELLS_PER_B;  // y*S + x
        const float4 v =
            *reinterpret_cast<const float4*>(enc + (size_t)agent * C + c4);
        unsigned* p = grid + ((size_t)b * C + c4) * CELLS_PER_B + rem;
        atomicMax(p,                      encode_f32(v.x));
        atomicMax(p + 1 * CELLS_PER_B,    encode_f32(v.y));
        atomicMax(p + 2 * CELLS_PER_B,    encode_f32(v.z));
        atomicMax(p + 3 * CELLS_PER_B,    encode_f32(v.w));
    }
}

// In-place decode: key -> float (0.0f for empty). Elementwise, uint4/lane.
__global__ void spatial_decode(unsigned* __restrict__ grid, int n4) {
    const int stride = gridDim.x * blockDim.x;
    uint4* g4 = reinterpret_cast<uint4*>(grid);
    for (int i = blockIdx.x * blockDim.x + threadIdx.x; i < n4; i += stride) {
        uint4 k = g4[i];
        float4 f;
        f.x = decode_key(k.x);
        f.y = decode_key(k.y);
        f.z = decode_key(k.z);
        f.w = decode_key(k.w);
        reinterpret_cast<float4*>(g4)[i] = f;
    }
}

extern "C" void kernel_launch(void* const* d_in, const int* in_sizes, int n_in,
                              void* d_out, int out_size, void* d_ws, size_t ws_size,
                              hipStream_t stream) {
    // setup_inputs order: batch_size (scalar), agent_encodings (N*C f32),
    // encode_coordinates (N int32).
    const float* enc = (const float*)d_in[1];
    const int* coords = (const int*)d_in[2];
    unsigned* out = (unsigned*)d_out;

    const int n_agents = in_sizes[2];
    const int C = in_sizes[1] / n_agents;  // 64

    // Phase 1: init grid keys to 0 (= empty marker).
    hipMemsetAsync(d_out, 0, (size_t)out_size * sizeof(float), stream);

    // Phase 2: scatter-max atomics directly into final layout.
    const int blocks = 2048, threads = 256;
    spatial_scatter_max<<<blocks, threads, 0, stream>>>(enc, coords, out,
                                                        n_agents, C);

    // Phase 3: in-place decode (out_size = B*C*S*S, divisible by 4).
    spatial_decode<<<blocks, threads, 0, stream>>>(out, out_size / 4);
}

// Round 2
// 131.476 us; speedup vs baseline: 18.4916x; 18.4916x over previous
//
#include <hip/hip_runtime.h>
#include <math.h>

// SpatialEncodeAgent: segment_max of agent_encodings (N,64) into a B*100*100
// grid, output [B, C, S, S] f32, 0 for empty cells.
//
// Round-2 strategy: the round-1 scatter (64M atomicMax over the 82 MB output)
// thrashed L2 (WRITE_SIZE = 2 GB for an 82 MB output, 24x writeback/line).
// Invert to a gather:
//   1) build per-cell linked lists: head[cell] (1.28 MB, L2-resident
//      atomicExch) + next[agent] (coalesced write). 1M small-surface atomics.
//   2) gather: 16 lanes per cell walk the chain; each chain step reads the
//      agent's 256B row as coalesced float4 x 16 lanes; fmax in registers;
//      output streamed exactly once (no memset needed - empties write 0).
// fmax is exactly commutative/associative -> chain-order nondeterminism does
// not change the result bitwise.

#define S_DIM 100
#define CELLS_PER_B (S_DIM * S_DIM)  // 10000 (divisible by 16 -> no block straddles a batch)
#define C_DIM 64

__global__ void build_lists(const int* __restrict__ coords,
                            int* __restrict__ head, int* __restrict__ next,
                            int n) {
    const int stride = gridDim.x * blockDim.x;
    for (int i = blockIdx.x * blockDim.x + threadIdx.x; i < n; i += stride) {
        const int c = coords[i];
        next[i] = atomicExch(&head[c], i);
    }
}

// Block = 256 threads = 16 cells x 16 lanes. Each lane owns 4 channels.
__global__ void gather_max(const float* __restrict__ enc,
                           const int* __restrict__ head,
                           const int* __restrict__ next,
                           float* __restrict__ out, int ncells) {
    __shared__ float tile[16][C_DIM + 1];  // +1 pad: conflict-free col read
    const int tid = threadIdx.x;
    const int cl = tid >> 4;         // local cell 0..15
    const int c4 = (tid & 15) << 2;  // channel base 0,4,...,60
    const int cell = blockIdx.x * 16 + cl;

    float4 m = make_float4(-INFINITY, -INFINITY, -INFINITY, -INFINITY);
    int agent = (cell < ncells) ? head[cell] : -1;
    const bool occupied = (agent >= 0);
    while (agent >= 0) {  // same-address head/next loads broadcast in the wave
        const float4 v =
            *reinterpret_cast<const float4*>(enc + (size_t)agent * C_DIM + c4);
        m.x = fmaxf(m.x, v.x);
        m.y = fmaxf(m.y, v.y);
        m.z = fmaxf(m.z, v.z);
        m.w = fmaxf(m.w, v.w);
        agent = next[agent];
    }
    if (!occupied) m = make_float4(0.f, 0.f, 0.f, 0.f);
    tile[cl][c4 + 0] = m.x;
    tile[cl][c4 + 1] = m.y;
    tile[cl][c4 + 2] = m.z;
    tile[cl][c4 + 3] = m.w;
    __syncthreads();

    // Streamed write: for each channel c, 16 consecutive cells (64B) written
    // by 16 consecutive lanes.
    const int cell0 = blockIdx.x * 16;
    const int b = cell0 / CELLS_PER_B;
    const int rem0 = cell0 - b * CELLS_PER_B;
    float* base = out + ((size_t)b * C_DIM) * CELLS_PER_B + rem0;
    for (int i = tid; i < 16 * C_DIM; i += 256) {
        const int c = i >> 4;
        const int j = i & 15;
        if (cell0 + j < ncells)
            base[(size_t)c * CELLS_PER_B + j] = tile[j][c];
    }
}

// ---------- fallback (round-1 atomic path) if ws too small ----------
__device__ __forceinline__ unsigned encode_f32(float f) {
    unsigned u = __float_as_uint(f);
    return (u & 0x80000000u) ? ~u : (u | 0x80000000u);
}
__device__ __forceinline__ float decode_key(unsigned k) {
    if (k == 0u) return 0.0f;
    return (k & 0x80000000u) ? __uint_as_float(k & 0x7FFFFFFFu)
                             : __uint_as_float(~k);
}
__global__ void spatial_scatter_max(const float* __restrict__ enc,
                                    const int* __restrict__ coords,
                                    unsigned* __restrict__ grid,
                                    int n_agents, int C) {
    const long long total = (long long)n_agents * 16;
    const long long stride = (long long)gridDim.x * blockDim.x;
    for (long long i = (long long)blockIdx.x * blockDim.x + threadIdx.x;
         i < total; i += stride) {
        const int agent = (int)(i >> 4);
        const int c4 = ((int)i & 15) << 2;
        const int coord = coords[agent];
        const int b = coord / CELLS_PER_B;
        const int rem = coord - b * CELLS_PER_B;
        const float4 v =
            *reinterpret_cast<const float4*>(enc + (size_t)agent * C + c4);
        unsigned* p = grid + ((size_t)b * C + c4) * CELLS_PER_B + rem;
        atomicMax(p, encode_f32(v.x));
        atomicMax(p + 1 * CELLS_PER_B, encode_f32(v.y));
        atomicMax(p + 2 * CELLS_PER_B, encode_f32(v.z));
        atomicMax(p + 3 * CELLS_PER_B, encode_f32(v.w));
    }
}
__global__ void spatial_decode(unsigned* __restrict__ grid, int n4) {
    const int stride = gridDim.x * blockDim.x;
    uint4* g4 = reinterpret_cast<uint4*>(grid);
    for (int i = blockIdx.x * blockDim.x + threadIdx.x; i < n4; i += stride) {
        uint4 k = g4[i];
        float4 f;
        f.x = decode_key(k.x);
        f.y = decode_key(k.y);
        f.z = decode_key(k.z);
        f.w = decode_key(k.w);
        reinterpret_cast<float4*>(g4)[i] = f;
    }
}

extern "C" void kernel_launch(void* const* d_in, const int* in_sizes, int n_in,
                              void* d_out, int out_size, void* d_ws, size_t ws_size,
                              hipStream_t stream) {
    const float* enc = (const float*)d_in[1];
    const int* coords = (const int*)d_in[2];
    const int n = in_sizes[2];
    const int ncells = out_size / C_DIM;  // B * 10000

    const size_t need = (size_t)ncells * 4 + (size_t)n * 4;
    if (ws_size >= need) {
        int* head = (int*)d_ws;
        int* next = head + ncells;
        hipMemsetAsync(head, 0xFF, (size_t)ncells * 4, stream);  // head = -1
        build_lists<<<2048, 256, 0, stream>>>(coords, head, next, n);
        gather_max<<<(ncells + 15) / 16, 256, 0, stream>>>(
            enc, head, next, (float*)d_out, ncells);
    } else {
        // fallback: round-1 atomic scatter path
        unsigned* out = (unsigned*)d_out;
        hipMemsetAsync(d_out, 0, (size_t)out_size * sizeof(float), stream);
        spatial_scatter_max<<<2048, 256, 0, stream>>>(enc, coords, out, n,
                                                      C_DIM);
        spatial_decode<<<2048, 256, 0, stream>>>(out, out_size / 4);
    }
}